// Round 1
// baseline (207.671 us; speedup 1.0000x reference)
//
#include <hip/hip_runtime.h>

typedef __attribute__((ext_vector_type(8))) short short8;
typedef __attribute__((ext_vector_type(4))) short short4v;
typedef __attribute__((ext_vector_type(4))) float floatx4;
typedef __attribute__((ext_vector_type(16))) float floatx16;

#define GLOBAL_AS __attribute__((address_space(1)))
#define LDS_AS __attribute__((address_space(3)))

__device__ __forceinline__ short f2bs(float f) {
    // RNE float -> bf16 (as short). Inputs finite here.
    union { float f; unsigned u; } v; v.f = f;
    unsigned r = v.u + 0x7fffu + ((v.u >> 16) & 1u);
    return (short)(r >> 16);
}

#if __has_builtin(__builtin_amdgcn_cvt_pk_bf16_f32)
typedef __attribute__((ext_vector_type(2))) __bf16 bf16x2;
__device__ __forceinline__ unsigned pk2(float a, float b) {
    union { bf16x2 v; unsigned u; } u;
    u.v = __builtin_amdgcn_cvt_pk_bf16_f32(a, b);
    return u.u;
}
#else
__device__ __forceinline__ unsigned pk2(float a, float b) {
    // round-half-up, non-negative finite inputs
    union { float f; unsigned u; } x, y; x.f = a; y.f = b;
    return ((y.u + 0x8000u) & 0xffff0000u) | ((x.u + 0x8000u) >> 16);
}
#endif

// ---------------- fused cast fp32 -> bf16 (x + Wq + Wk + Wv) ----------------
__global__ __launch_bounds__(256) void cast_all(const float* __restrict__ x,
                                                const float* __restrict__ Wq,
                                                const float* __restrict__ Wk,
                                                const float* __restrict__ Wv,
                                                short* __restrict__ xb,
                                                short* __restrict__ wb) {
    int b = blockIdx.x;
    int t = threadIdx.x;
    const float* src;
    short* dst;
    int idx;
    if (b < 8192) {
        src = x; dst = xb; idx = b * 1024 + t * 4;
    } else {
        int r = b - 8192;
        int wz = r >> 10;
        src = (wz == 0) ? Wq : (wz == 1) ? Wk : Wv;
        dst = wb + wz * (1 << 20);
        idx = (r & 1023) * 1024 + t * 4;
    }
    float4 v = *(const float4*)(src + idx);
    short4v o;
    o.x = f2bs(v.x); o.y = f2bs(v.y); o.z = f2bs(v.z); o.w = f2bs(v.w);
    *(short4v*)(dst + idx) = o;
}

// ---------------- QKV GEMM v2: 256x256 tile, 8-wave, pipelined 4-phase/K-tile ----------------
// A = xb [8192,1024], B = wb [3072,1024] (Q|K|V fused in N). BK=64, LDS 128 KiB dbuf.
// Per wave: 128x64 output (acc[8][4]); per phase: one 64x32 C-quadrant x K=64 = 16 MFMA.
// Stage stream (quarter-tiles Au0,Bu0,Bu1,Au1 of tile T+1 issued at T.P0..P3) matched to
// quadrant read order (0,0)(0,1)(1,1)(1,0); counted vmcnt(4) (never 0 in main loop).
// Ledger (steady state, 2 loads/unit): enter T.P0 outstanding={T:Bu1,Au1}; P0 +T1Au0 -> 6,
// vm4 completes T:Bu1 (need P1); P1 +T1Bu0 -> 6, vm4 completes T:Au1 (need P2); P2 +T1Bu1 -> 6,
// no wait; P3 +T1Au1 -> 8, vm4 completes T1:{Au0,Bu0} (need T1.P0). Tail stages dummy tile 0.
__global__ __launch_bounds__(512, 2) void qkv_gemm(const short* __restrict__ xb,
                                                   const short* __restrict__ wb,
                                                   short* __restrict__ qout,
                                                   short* __restrict__ kout,
                                                   short* __restrict__ vtout) {
    __shared__ short As[32768];  // 2 x [256][64], 16B chunks XOR-swizzled: slot = chunk ^ (row&7)
    __shared__ short Bs[32768];
    const int K = 1024;
    int tid = threadIdx.x;
    int lane = tid & 63;
    int wid = tid >> 6;
    int quad = lane >> 4;
    int l16 = lane & 15;
    int wm = (wid >> 2) * 128;  // WARPS_M=2
    int wn = (wid & 3) * 64;    // WARPS_N=4

    int flat = blockIdx.x;                     // 384 blocks, 384%8==0 -> simple bijective swizzle
    int swz = (flat & 7) * 48 + (flat >> 3);   // 48 consecutive per XCD
    int bx = swz / 12;                         // 0..31 -> M tile
    int by = swz - bx * 12;                    // 0..11 -> fused-N tile (wz = by>>2)
    int bm = bx * 256;

    const short* A0 = xb + (size_t)bm * K;
    const short* B0 = wb + (size_t)(by * 256) * K;

    int srow = tid >> 3;
    int sw = ((tid & 7) ^ (srow & 7)) * 8;  // source-side swizzle (LDS dest stays linear)
    const short* gA = A0 + (size_t)srow * K + sw;
    const short* gB = B0 + (size_t)(((tid >> 8) << 6) + (srow & 31)) * K + sw;
    short* ldsA = As + tid * 8;
    short* ldsB = Bs + ((tid >> 8) << 12) + (tid & 255) * 8;

#define STAGE_AU(nb, u, kkn) do { \
    __builtin_amdgcn_global_load_lds((const GLOBAL_AS void*)(gA + (size_t)((u) * 64) * 1024 + (kkn)), \
        (LDS_AS void*)(ldsA + (nb) * 16384 + (u) * 4096), 16, 0, 0); \
    __builtin_amdgcn_global_load_lds((const GLOBAL_AS void*)(gA + (size_t)(128 + (u) * 64) * 1024 + (kkn)), \
        (LDS_AS void*)(ldsA + (nb) * 16384 + 8192 + (u) * 4096), 16, 0, 0); \
} while (0)
#define STAGE_BU(nb, u, kkn) do { \
    __builtin_amdgcn_global_load_lds((const GLOBAL_AS void*)(gB + (size_t)((u) * 32) * 1024 + (kkn)), \
        (LDS_AS void*)(ldsB + (nb) * 16384 + (u) * 2048), 16, 0, 0); \
    __builtin_amdgcn_global_load_lds((const GLOBAL_AS void*)(gB + (size_t)(128 + (u) * 32) * 1024 + (kkn)), \
        (LDS_AS void*)(ldsB + (nb) * 16384 + 8192 + (u) * 2048), 16, 0, 0); \
} while (0)

#define BARX() __builtin_amdgcn_s_barrier()
#define SBAR() __builtin_amdgcn_sched_barrier(0)
#define LGKM0() asm volatile("s_waitcnt lgkmcnt(0)" ::: "memory")
#define VM4() asm volatile("s_waitcnt vmcnt(4)" ::: "memory")

#define LDA_(Ab, Qm) do { int xx = l16 & 7; \
    _Pragma("unroll") for (int i = 0; i < 4; i++) { \
        const short* rp = (Ab) + (wm + (Qm) * 64 + i * 16 + l16) * 64; \
        aF[i][0] = *(const short8*)(rp + (quad ^ xx) * 8); \
        aF[i][1] = *(const short8*)(rp + ((4 | quad) ^ xx) * 8); \
    } } while (0)
#define LDB_(Bb, Qn, bf) do { int xx = l16 & 7; \
    _Pragma("unroll") for (int j = 0; j < 2; j++) { \
        const short* rp = (Bb) + (wn + (Qn) * 32 + j * 16 + l16) * 64; \
        bf[j][0] = *(const short8*)(rp + (quad ^ xx) * 8); \
        bf[j][1] = *(const short8*)(rp + ((4 | quad) ^ xx) * 8); \
    } } while (0)
#define MM_(Qm, Qn, bf) do { \
    __builtin_amdgcn_s_setprio(1); \
    _Pragma("unroll") for (int s = 0; s < 2; s++) \
    _Pragma("unroll") for (int i = 0; i < 4; i++) \
    _Pragma("unroll") for (int j = 0; j < 2; j++) \
        acc[(Qm) * 4 + i][(Qn) * 2 + j] = __builtin_amdgcn_mfma_f32_16x16x32_bf16( \
            aF[i][s], bf[j][s], acc[(Qm) * 4 + i][(Qn) * 2 + j], 0, 0, 0); \
    __builtin_amdgcn_s_setprio(0); \
} while (0)

    floatx4 acc[8][4];
#pragma unroll
    for (int i = 0; i < 8; i++)
#pragma unroll
        for (int j = 0; j < 4; j++) acc[i][j] = (floatx4){0.f, 0.f, 0.f, 0.f};
    short8 aF[4][2], bF0[2][2], bF1[2][2];

    // prologue: tile 0 -> buf 0 (Au0,Bu0,Bu1,Au1); vm4 leaves {Bu1,Au1} in flight
    STAGE_AU(0, 0, 0); STAGE_BU(0, 0, 0); STAGE_BU(0, 1, 0); STAGE_AU(0, 1, 0);
    VM4(); BARX(); SBAR();

#pragma unroll 2
    for (int T = 0; T < 16; T++) {
        const short* Ab = As + (T & 1) * 16384;
        const short* Bb = Bs + (T & 1) * 16384;
        int nb = (T & 1) ^ 1;
        int kkn = ((T + 1) & 15) << 6;  // T=15 stages dummy tile 0 (keeps vmcnt ledger uniform)
        // P0: quadrant (0,0)
        LDA_(Ab, 0); LDB_(Bb, 0, bF0);
        STAGE_AU(nb, 0, kkn);
        BARX(); LGKM0(); SBAR();
        MM_(0, 0, bF0);
        VM4(); BARX(); SBAR();
        // P1: (0,1)
        LDB_(Bb, 1, bF1);
        STAGE_BU(nb, 0, kkn);
        BARX(); LGKM0(); SBAR();
        MM_(0, 1, bF1);
        VM4(); BARX(); SBAR();
        // P2: (1,1)
        LDA_(Ab, 1);
        STAGE_BU(nb, 1, kkn);
        BARX(); LGKM0(); SBAR();
        MM_(1, 1, bF1);
        BARX(); SBAR();
        // P3: (1,0) — no ds_reads (bF0 held in regs since P0)
        STAGE_AU(nb, 1, kkn);
        BARX(); SBAR();
        MM_(1, 0, bF0);
        VM4(); BARX(); SBAR();
    }

    // ---- epilogue (same verified C/D mapping as before) ----
    int wz = by >> 2;
    int cb = (by & 3) * 256 + wn;
    if (wz == 2) {
#pragma unroll
        for (int mi = 0; mi < 8; mi++) {
#pragma unroll
            for (int ni = 0; ni < 4; ni++) {
                int m = bm + wm + mi * 16 + quad * 4;
                int c = cb + ni * 16 + l16;
                int b = m >> 11, nn = m & 2047, h = c >> 6, dd = c & 63;
                short4v pk;
                pk.x = f2bs(acc[mi][ni][0]);
                pk.y = f2bs(acc[mi][ni][1]);
                pk.z = f2bs(acc[mi][ni][2]);
                pk.w = f2bs(acc[mi][ni][3]);
                *(short4v*)(vtout + ((size_t)(b * 16 + h) * 64 + dd) * 2048 + nn) = pk;
            }
        }
    } else {
        short* dst = wz ? kout : qout;
        float qs = wz ? 1.0f : 0.180336881f;  // 0.125*log2(e) folded into Q
#pragma unroll
        for (int mi = 0; mi < 8; mi++) {
#pragma unroll
            for (int ni = 0; ni < 4; ni++) {
#pragma unroll
                for (int r = 0; r < 4; r++) {
                    int m = bm + wm + mi * 16 + quad * 4 + r;
                    int c = cb + ni * 16 + l16;
                    dst[((size_t)((m >> 11) * 16 + (c >> 6)) * 2048 + (m & 2047)) * 64 + (c & 63)] =
                        f2bs(acc[mi][ni][r] * qs);
                }
            }
        }
    }
}

// ---------------- Flash attention: 32x32x16 MFMA, S^T trick, Q128/KV128 ----------------
// q: pre-scaled bf16 [b,h,2048,64]; k: [b,h,2048,64]; vt: [b,h,64,2048]; out fp32 [b,2048,1024]
// Block = 256 thr (4 waves x 32 qrows = 128-row Q tile). Pair (qx,15-qx) -> 17 KV-128 tiles.
// 512 blocks, XCD-swizzled: 8 (b,h) per XCD (K+V = 4 MB = one L2); exactly 2 blocks/CU.
// S^T = K*Q^T so each lane owns ONE q-column: local row-sums, b64-packed P writes.
__global__ __launch_bounds__(256, 2) void attn(const short* __restrict__ q,
                                               const short* __restrict__ k,
                                               const short* __restrict__ vt,
                                               float* __restrict__ out) {
    __shared__ short Ks[128 * 64];      // [key][d], 16B slot = chunk ^ (key&7)
    __shared__ short Vs[64 * 128];      // [d][key], 16B slot = (c&8)|((c^(d&7))&7)
    __shared__ short Ps[4 * 32 * 136];  // per-wave P [qrow 0..31][key], stride 136 shorts

    int tid = threadIdx.x;
    int lane = tid & 63;
    int wid = tid >> 6;
    int l32 = lane & 31;
    int half = lane >> 5;   // 0/1

    int flat = blockIdx.x;
    int xcd = flat & 7;
    int slot = flat >> 3;            // 0..63
    int bh = xcd * 8 + (slot >> 3);  // 8 (b,h) per XCD
    int qx = slot & 7;
    int b = bh >> 4, h = bh & 15;

    const short* qp = q + (size_t)(b * 16 + h) * 2048 * 64;
    const short* kp = k + (size_t)(b * 16 + h) * 2048 * 64;
    const short* vp = vt + (size_t)(b * 16 + h) * 64 * 2048;

    // K staging: 128x64. row = (tid>>3)+l*32, chunk = tid&7 (swizzled at source)
    int krow = tid >> 3;
    int ksw = ((tid & 7) ^ (krow & 7)) * 8;
    // V staging: 64x128. d = (tid>>4)+l*16, chunk16 = tid&15
    int vd = tid >> 4;
    int vc = tid & 15;
    int vsw = ((vc & 8) | ((vc ^ vd) & 7)) * 8;

    short* pw = Ps + wid * (32 * 136);

    for (int phase = 0; phase < 2; phase++) {
        int qt = (phase == 0) ? qx : (15 - qx);
        int qbase = qt * 128;
        int qrow_w = qbase + wid * 32;      // wave owns q-rows qrow_w .. qrow_w+31
        int qlane = qrow_w + l32;           // this lane's q-row (S^T col)

        // Q fragments as B-operand: n = l32 (q-row), k = half*8 + j, 4 K-steps over d=64
        short8 qf[4];
#pragma unroll
        for (int s = 0; s < 4; s++)
            qf[s] = *(const short8*)(qp + (size_t)qlane * 64 + s * 16 + half * 8);

        floatx16 oacc[2];
#pragma unroll
        for (int nt = 0; nt < 2; nt++)
#pragma unroll
            for (int e = 0; e < 16; e++) oacc[nt][e] = 0.f;
        float rs = 0.f;

        int ntiles = qt + 1;
        for (int t = 0; t < ntiles; t++) {
            int kvb = t * 128;
            __syncthreads();
#pragma unroll
            for (int l = 0; l < 4; l++) {
                const short* g = kp + (size_t)(kvb + krow + l * 32) * 64 + ksw;
                __builtin_amdgcn_global_load_lds((const GLOBAL_AS void*)g,
                                                 (LDS_AS void*)(Ks + tid * 8 + l * 2048), 16, 0, 0);
            }
#pragma unroll
            for (int l = 0; l < 4; l++) {
                const short* g = vp + (size_t)(vd + l * 16) * 2048 + kvb + vsw;
                __builtin_amdgcn_global_load_lds((const GLOBAL_AS void*)g,
                                                 (LDS_AS void*)(Vs + tid * 8 + l * 2048), 16, 0, 0);
            }
            __syncthreads();

            // ---- S^T[key 0..127][q 0..31] = K * Q^T ----
            floatx16 sacc[4];
#pragma unroll
            for (int kb = 0; kb < 4; kb++)
#pragma unroll
                for (int e = 0; e < 16; e++) sacc[kb][e] = 0.f;
#pragma unroll
            for (int s = 0; s < 4; s++) {   // d-dim K-steps
#pragma unroll
                for (int kb = 0; kb < 4; kb++) {
                    int key = kb * 32 + l32;
                    int c = s * 2 + half;
                    short8 kf = *(const short8*)(Ks + key * 64 + ((c ^ (key & 7)) * 8));
                    sacc[kb] = __builtin_amdgcn_mfma_f32_32x32x16_bf16(kf, qf[s], sacc[kb], 0, 0, 0);
                }
            }

            // ---- exp2 + mask (diag tile only) + local row-sum + packed P write ----
            bool diag = (t == ntiles - 1) && (phase >= 0) && (kvb + 127 > qrow_w);
#pragma unroll
            for (int kb = 0; kb < 4; kb++) {
#pragma unroll
                for (int e = 0; e < 16; e++) {
                    float p = __builtin_amdgcn_exp2f(sacc[kb][e]);
                    if (diag) {
                        int key = kvb + kb * 32 + (e & 3) + 8 * (e >> 2) + 4 * half;
                        p = (key > qlane) ? 0.f : p;
                    }
                    sacc[kb][e] = p;
                    rs += p;
                }
                // C/D reg-quads hold 4 consecutive keys -> b64 writes
#pragma unroll
                for (int g = 0; g < 4; g++) {
                    int2 wv;
                    wv.x = pk2(sacc[kb][4 * g], sacc[kb][4 * g + 1]);
                    wv.y = pk2(sacc[kb][4 * g + 2], sacc[kb][4 * g + 3]);
                    *(int2*)(pw + l32 * 136 + kb * 32 + g * 8 + 4 * half) = wv;
                }
            }
            __threadfence_block();

            // ---- O += P * V : A = P[q][key], B = V^T[d][key] ----
#pragma unroll
            for (int s = 0; s < 8; s++) {   // key K-steps of 16
                short8 pf = *(const short8*)(pw + l32 * 136 + s * 16 + half * 8);
#pragma unroll
                for (int nt = 0; nt < 2; nt++) {
                    int d = nt * 32 + l32;
                    int c = s * 2 + half;
                    int sl = (c & 8) | ((c ^ (d & 7)) & 7);
                    short8 vf = *(const short8*)(Vs + d * 128 + sl * 8);
                    oacc[nt] = __builtin_amdgcn_mfma_f32_32x32x16_bf16(pf, vf, oacc[nt], 0, 0, 0);
                }
            }
        }

        // ---- epilogue: rows of O live across lanes; fetch 1/l via shuffle ----
        float tot = rs + __shfl_xor(rs, 32);
        float inv = 1.0f / tot;
        float invr[16];
#pragma unroll
        for (int e = 0; e < 16; e++)
            invr[e] = __shfl(inv, (e & 3) + 8 * (e >> 2) + 4 * half);
#pragma unroll
        for (int nt = 0; nt < 2; nt++) {
#pragma unroll
            for (int e = 0; e < 16; e++) {
                int r = (e & 3) + 8 * (e >> 2) + 4 * half;
                int nn = qrow_w + r;
                out[((size_t)b * 2048 + nn) * 1024 + h * 64 + nt * 32 + l32] = oacc[nt][e] * invr[e];
            }
        }
    }
}

extern "C" void kernel_launch(void* const* d_in, const int* in_sizes, int n_in,
                              void* d_out, int out_size, void* d_ws, size_t ws_size,
                              hipStream_t stream) {
    const float* x = (const float*)d_in[0];
    const float* Wq = (const float*)d_in[1];
    const float* Wk = (const float*)d_in[2];
    const float* Wv = (const float*)d_in[3];
    float* out = (float*)d_out;
    char* ws = (char*)d_ws;

    short* xb = (short*)ws;                          // 16 MB: [8192,1024] bf16
    short* wb = (short*)(ws + (16u << 20));          //  6 MB: [3,1024,1024] bf16
    short* qb = (short*)(ws + (22u << 20));          // 16 MB: [4,16,2048,64]
    short* kb = (short*)(ws + (38u << 20));          // 16 MB: [4,16,2048,64]
    short* vtb = (short*)(ws + (54u << 20));         // 16 MB: [4,16,64,2048]

    cast_all<<<8192 + 3 * 1024, 256, 0, stream>>>(x, Wq, Wk, Wv, xb, wb);
    qkv_gemm<<<384, 512, 0, stream>>>(xb, wb, qb, kb, vtb);
    attn<<<512, 256, 0, stream>>>(qb, kb, vtb, out);
}

// Round 3
// 204.906 us; speedup vs baseline: 1.0135x; 1.0135x over previous
//
#include <hip/hip_runtime.h>

typedef __attribute__((ext_vector_type(8))) short short8;
typedef __attribute__((ext_vector_type(4))) short short4v;
typedef __attribute__((ext_vector_type(4))) float floatx4;
typedef __attribute__((ext_vector_type(16))) float floatx16;
typedef __attribute__((ext_vector_type(2))) int iv2;

#define GLOBAL_AS __attribute__((address_space(1)))
#define LDS_AS __attribute__((address_space(3)))

__device__ __forceinline__ short f2bs(float f) {
    // RNE float -> bf16 (as short). Inputs finite here.
    union { float f; unsigned u; } v; v.f = f;
    unsigned r = v.u + 0x7fffu + ((v.u >> 16) & 1u);
    return (short)(r >> 16);
}

#if __has_builtin(__builtin_amdgcn_cvt_pk_bf16_f32)
typedef __attribute__((ext_vector_type(2))) __bf16 bf16x2;
__device__ __forceinline__ unsigned pk2(float a, float b) {
    union { bf16x2 v; unsigned u; } u;
    u.v = __builtin_amdgcn_cvt_pk_bf16_f32(a, b);
    return u.u;
}
#else
__device__ __forceinline__ unsigned pk2(float a, float b) {
    // round-half-up, non-negative finite inputs
    union { float f; unsigned u; } x, y; x.f = a; y.f = b;
    return ((y.u + 0x8000u) & 0xffff0000u) | ((x.u + 0x8000u) >> 16);
}
#endif

// ---------------- fused cast fp32 -> bf16 (x + Wq + Wk + Wv) ----------------
__global__ __launch_bounds__(256) void cast_all(const float* __restrict__ x,
                                                const float* __restrict__ Wq,
                                                const float* __restrict__ Wk,
                                                const float* __restrict__ Wv,
                                                short* __restrict__ xb,
                                                short* __restrict__ wb) {
    int b = blockIdx.x;
    int t = threadIdx.x;
    const float* src;
    short* dst;
    int idx;
    if (b < 8192) {
        src = x; dst = xb; idx = b * 1024 + t * 4;
    } else {
        int r = b - 8192;
        int wz = r >> 10;
        src = (wz == 0) ? Wq : (wz == 1) ? Wk : Wv;
        dst = wb + wz * (1 << 20);
        idx = (r & 1023) * 1024 + t * 4;
    }
    float4 v = *(const float4*)(src + idx);
    short4v o;
    o.x = f2bs(v.x); o.y = f2bs(v.y); o.z = f2bs(v.z); o.w = f2bs(v.w);
    *(short4v*)(dst + idx) = o;
}

// ---------------- QKV GEMM: P = xb @ W^T, BK=64 (proven R0 version) ----------------
__global__ __launch_bounds__(256) void qkv_gemm(const short* __restrict__ xb,
                                                const short* __restrict__ wb,
                                                short* __restrict__ qout,
                                                short* __restrict__ kout,
                                                short* __restrict__ vtout) {
    __shared__ short As[128 * 64];  // [m][k], 16B chunks XOR-swizzled: slot = chunk ^ (row&7)
    __shared__ short Bs[128 * 64];
    const int K = 1024;
    int tid = threadIdx.x;
    int lane = tid & 63;
    int wid = tid >> 6;
    int quad = lane >> 4;
    int l16 = lane & 15;
    int wm = (wid >> 1) * 64;
    int wn = (wid & 1) * 64;
    int bm = blockIdx.x * 128;
    int bn = blockIdx.y * 128;
    const short* W = wb + (size_t)blockIdx.z * K * 1024;

    floatx4 acc[4][4];
#pragma unroll
    for (int i = 0; i < 4; i++)
#pragma unroll
        for (int j = 0; j < 4; j++) acc[i][j] = (floatx4){0.f, 0.f, 0.f, 0.f};

    int srow = tid >> 3;
    int ssw = ((tid & 7) ^ (srow & 7)) * 8;

    for (int kk = 0; kk < K; kk += 64) {
        __syncthreads();
#pragma unroll
        for (int l = 0; l < 4; l++) {
            const short* g = xb + (size_t)(bm + srow + l * 32) * K + kk + ssw;
            __builtin_amdgcn_global_load_lds((const GLOBAL_AS void*)g,
                                             (LDS_AS void*)(As + tid * 8 + l * 2048), 16, 0, 0);
        }
#pragma unroll
        for (int l = 0; l < 4; l++) {
            const short* g = W + (size_t)(bn + srow + l * 32) * K + kk + ssw;
            __builtin_amdgcn_global_load_lds((const GLOBAL_AS void*)g,
                                             (LDS_AS void*)(Bs + tid * 8 + l * 2048), 16, 0, 0);
        }
        __syncthreads();

#pragma unroll
        for (int s = 0; s < 2; s++) {
            int slot = ((s * 4 + quad) ^ (l16 & 7)) * 8;
            short8 af[4], bf[4];
#pragma unroll
            for (int i = 0; i < 4; i++)
                af[i] = *(const short8*)(As + (wm + i * 16 + l16) * 64 + slot);
#pragma unroll
            for (int j = 0; j < 4; j++)
                bf[j] = *(const short8*)(Bs + (wn + j * 16 + l16) * 64 + slot);
#pragma unroll
            for (int i = 0; i < 4; i++)
#pragma unroll
                for (int j = 0; j < 4; j++)
                    acc[i][j] = __builtin_amdgcn_mfma_f32_16x16x32_bf16(af[i], bf[j], acc[i][j], 0, 0, 0);
        }
    }

    if (blockIdx.z == 2) {
#pragma unroll
        for (int i = 0; i < 4; i++) {
#pragma unroll
            for (int j = 0; j < 4; j++) {
                int m = bm + wm + i * 16 + quad * 4;
                int c = bn + wn + j * 16 + l16;
                int b = m >> 11, nn = m & 2047, h = c >> 6, dd = c & 63;
                short4v pk;
                pk.x = f2bs(acc[i][j][0]);
                pk.y = f2bs(acc[i][j][1]);
                pk.z = f2bs(acc[i][j][2]);
                pk.w = f2bs(acc[i][j][3]);
                *(short4v*)(vtout + ((size_t)(b * 16 + h) * 64 + dd) * 2048 + nn) = pk;
            }
        }
    } else {
        short* dst = (blockIdx.z == 0) ? qout : kout;
        float qs = (blockIdx.z == 0) ? 0.180336881f : 1.0f;  // 0.125*log2(e) folded into Q
#pragma unroll
        for (int i = 0; i < 4; i++) {
#pragma unroll
            for (int j = 0; j < 4; j++) {
#pragma unroll
                for (int r = 0; r < 4; r++) {
                    int m = bm + wm + i * 16 + quad * 4 + r;
                    int c = bn + wn + j * 16 + l16;
                    dst[((size_t)((m >> 11) * 16 + (c >> 6)) * 2048 + (m & 2047)) * 64 + (c & 63)] =
                        f2bs(acc[i][j][r] * qs);
                }
            }
        }
    }
}

// ---------------- Flash attention v2b: in-register P (permlane32_swap, FIXED) + K/V dbuf ----------------
// q: pre-scaled bf16 [b,h,2048,64]; k: [b,h,2048,64]; vt: [b,h,64,2048]; out fp32 [b,2048,1024]
// S^T = K*Q^T: lane owns ONE q-column. P never touches LDS.
// Exchange derivation (C/D map row=(e&3)+8(e>>2)+4*half): for K-step s (sb=s&1), consumer half h
// needs keys 16sb+8h+{0..7}, ALL from quad g=2sb+h: j0..3 from half-0 owner, j4..7 from half-1 owner.
// permlane32_swap(a=W[2sb], b=W[2sb+1]) -> r.x = {a_low, b_low} = j01/j23 dword for both halves,
// r.y = {a_high, b_high} = j45/j67 dword for both halves.
__global__ __launch_bounds__(256, 2) void attn(const short* __restrict__ q,
                                               const short* __restrict__ k,
                                               const short* __restrict__ vt,
                                               float* __restrict__ out) {
    __shared__ short Ks[2][128 * 64];   // [key][d], 16B slot = chunk ^ (key&7)
    __shared__ short Vs[2][64 * 128];   // [d][key], 16B slot = (c&8)|((c^(d&7))&7)

    int tid = threadIdx.x;
    int lane = tid & 63;
    int wid = tid >> 6;
    int l32 = lane & 31;
    int half = lane >> 5;   // 0/1

    int flat = blockIdx.x;
    int xcd = flat & 7;
    int slot = flat >> 3;            // 0..63
    int bh = xcd * 8 + (slot >> 3);  // 8 (b,h) per XCD
    int qx = slot & 7;
    int b = bh >> 4, h = bh & 15;

    const short* qp = q + (size_t)(b * 16 + h) * 2048 * 64;
    const short* kp = k + (size_t)(b * 16 + h) * 2048 * 64;
    const short* vp = vt + (size_t)(b * 16 + h) * 64 * 2048;

    // K staging: 128x64. row = (tid>>3)+l*32, chunk = tid&7 (swizzled at source)
    int krow = tid >> 3;
    int ksw = ((tid & 7) ^ (krow & 7)) * 8;
    // V staging: 64x128. d = (tid>>4)+l*16, chunk16 = tid&15
    int vd = tid >> 4;
    int vc = tid & 15;
    int vsw = ((vc & 8) | ((vc ^ vd) & 7)) * 8;

#define STAGE_KV(cb, kvb) do { \
    _Pragma("unroll") for (int l = 0; l < 4; l++) { \
        const short* g = kp + (size_t)((kvb) + krow + l * 32) * 64 + ksw; \
        __builtin_amdgcn_global_load_lds((const GLOBAL_AS void*)g, \
            (LDS_AS void*)(&Ks[cb][0] + tid * 8 + l * 2048), 16, 0, 0); \
    } \
    _Pragma("unroll") for (int l = 0; l < 4; l++) { \
        const short* g = vp + (size_t)(vd + l * 16) * 2048 + (kvb) + vsw; \
        __builtin_amdgcn_global_load_lds((const GLOBAL_AS void*)g, \
            (LDS_AS void*)(&Vs[cb][0] + tid * 8 + l * 2048), 16, 0, 0); \
    } \
} while (0)

    for (int phase = 0; phase < 2; phase++) {
        int qt = (phase == 0) ? qx : (15 - qx);
        int qbase = qt * 128;
        int qrow_w = qbase + wid * 32;      // wave owns q-rows qrow_w .. qrow_w+31
        int qlane = qrow_w + l32;           // this lane's q-row (S^T col)

        // Q fragments as B-operand: n = l32 (q-row), k = half*8 + j, 4 K-steps over d=64
        short8 qf[4];
#pragma unroll
        for (int s = 0; s < 4; s++)
            qf[s] = *(const short8*)(qp + (size_t)qlane * 64 + s * 16 + half * 8);

        floatx16 oacc[2];
#pragma unroll
        for (int nt = 0; nt < 2; nt++)
#pragma unroll
            for (int e = 0; e < 16; e++) oacc[nt][e] = 0.f;
        float rs = 0.f;

        int ntiles = qt + 1;

        // phase prologue: guard vs previous phase's reads of buf0, then stage tile 0
        __builtin_amdgcn_sched_barrier(0);
        __builtin_amdgcn_s_barrier();
        __builtin_amdgcn_sched_barrier(0);
        STAGE_KV(0, 0);

        for (int t = 0; t < ntiles; t++) {
            int cur = t & 1;
            int kvb = t * 128;

            // write-after-read guard: all waves done reading buf[cur^1] (tile t-1)
            __builtin_amdgcn_sched_barrier(0);
            __builtin_amdgcn_s_barrier();
            __builtin_amdgcn_sched_barrier(0);
            if (t + 1 < ntiles) {
                STAGE_KV(cur ^ 1, kvb + 128);
                asm volatile("s_waitcnt vmcnt(8)" ::: "memory");  // tile-t loads (mine) done
            } else {
                asm volatile("s_waitcnt vmcnt(0)" ::: "memory");
            }
            __builtin_amdgcn_sched_barrier(0);
            __builtin_amdgcn_s_barrier();   // tile-t LDS visible to all waves
            __builtin_amdgcn_sched_barrier(0);

            const short* Kc = &Ks[cur][0];
            const short* Vc = &Vs[cur][0];

            // ---- S^T[key 0..127][q 0..31] = K * Q^T ----
            floatx16 sacc[4];
#pragma unroll
            for (int kb = 0; kb < 4; kb++)
#pragma unroll
                for (int e = 0; e < 16; e++) sacc[kb][e] = 0.f;
#pragma unroll
            for (int s = 0; s < 4; s++) {   // d-dim K-steps
#pragma unroll
                for (int kb = 0; kb < 4; kb++) {
                    int key = kb * 32 + l32;
                    int c = s * 2 + half;
                    short8 kf = *(const short8*)(Kc + key * 64 + ((c ^ (key & 7)) * 8));
                    sacc[kb] = __builtin_amdgcn_mfma_f32_32x32x16_bf16(kf, qf[s], sacc[kb], 0, 0, 0);
                }
            }

            // ---- exp2 + mask (diag tile only) + local row-sum + in-register pack ----
            // quad g of block kb holds keys kb*32 + 8g + 4*half + {0..3} for q=l32:
            //   W0 = pk2(keys+0,+1), W1 = pk2(keys+2,+3)
            bool diag = (t == ntiles - 1) && (kvb + 127 > qrow_w);
            unsigned W0[4][4], W1[4][4];
#pragma unroll
            for (int kb = 0; kb < 4; kb++) {
#pragma unroll
                for (int e = 0; e < 16; e++) {
                    float p = __builtin_amdgcn_exp2f(sacc[kb][e]);
                    if (diag) {
                        int key = kvb + kb * 32 + (e & 3) + 8 * (e >> 2) + 4 * half;
                        p = (key > qlane) ? 0.f : p;
                    }
                    sacc[kb][e] = p;
                    rs += p;
                }
#pragma unroll
                for (int g = 0; g < 4; g++) {
                    W0[kb][g] = pk2(sacc[kb][4 * g + 0], sacc[kb][4 * g + 1]);
                    W1[kb][g] = pk2(sacc[kb][4 * g + 2], sacc[kb][4 * g + 3]);
                }
            }

            // ---- O += P * V : A-frag P[q=l32][keys 16s + 8*half + 0..7] via permlane32_swap ----
            // r0 = swap(W0[2sb], W0[2sb+1]): r0.x -> dword0 (keys +0,+1), r0.y -> dword2 (+4,+5)
            // r1 = swap(W1[2sb], W1[2sb+1]): r1.x -> dword1 (+2,+3),      r1.y -> dword3 (+6,+7)
#pragma unroll
            for (int s = 0; s < 8; s++) {   // key K-steps of 16
                int kb = s >> 1;
                int g0 = (s & 1) * 2;       // quad for half-0 consumers
                int g1 = g0 + 1;            // quad for half-1 consumers
                iv2 r0 = __builtin_amdgcn_permlane32_swap(W0[kb][g0], W0[kb][g1], false, false);
                iv2 r1 = __builtin_amdgcn_permlane32_swap(W1[kb][g0], W1[kb][g1], false, false);
                union { int4 v; short8 s8; } pu;
                pu.v.x = r0.x; pu.v.y = r1.x; pu.v.z = r0.y; pu.v.w = r1.y;
                short8 pf = pu.s8;
#pragma unroll
                for (int nt = 0; nt < 2; nt++) {
                    int d = nt * 32 + l32;
                    int c = s * 2 + half;
                    int sl = (c & 8) | ((c ^ (d & 7)) & 7);
                    short8 vf = *(const short8*)(Vc + d * 128 + sl * 8);
                    oacc[nt] = __builtin_amdgcn_mfma_f32_32x32x16_bf16(pf, vf, oacc[nt], 0, 0, 0);
                }
            }
        }

        // ---- epilogue: rows of O live across lanes; fetch 1/l via shuffle ----
        float tot = rs + __shfl_xor(rs, 32);
        float inv = 1.0f / tot;
        float invr[16];
#pragma unroll
        for (int e = 0; e < 16; e++)
            invr[e] = __shfl(inv, (e & 3) + 8 * (e >> 2) + 4 * half);
#pragma unroll
        for (int nt = 0; nt < 2; nt++) {
#pragma unroll
            for (int e = 0; e < 16; e++) {
                int r = (e & 3) + 8 * (e >> 2) + 4 * half;
                int nn = qrow_w + r;
                out[((size_t)b * 2048 + nn) * 1024 + h * 64 + nt * 32 + l32] = oacc[nt][e] * invr[e];
            }
        }
    }
#undef STAGE_KV
}

extern "C" void kernel_launch(void* const* d_in, const int* in_sizes, int n_in,
                              void* d_out, int out_size, void* d_ws, size_t ws_size,
                              hipStream_t stream) {
    const float* x = (const float*)d_in[0];
    const float* Wq = (const float*)d_in[1];
    const float* Wk = (const float*)d_in[2];
    const float* Wv = (const float*)d_in[3];
    float* out = (float*)d_out;
    char* ws = (char*)d_ws;

    short* xb = (short*)ws;                          // 16 MB: [8192,1024] bf16
    short* wb = (short*)(ws + (16u << 20));          //  6 MB: [3,1024,1024] bf16
    short* qb = (short*)(ws + (22u << 20));          // 16 MB: [4,16,2048,64]
    short* kb = (short*)(ws + (38u << 20));          // 16 MB: [4,16,2048,64]
    short* vtb = (short*)(ws + (54u << 20));         // 16 MB: [4,16,64,2048]

    cast_all<<<8192 + 3 * 1024, 256, 0, stream>>>(x, Wq, Wk, Wv, xb, wb);
    qkv_gemm<<<dim3(64, 8, 3), 256, 0, stream>>>(xb, wb, qb, kb, vtb);
    attn<<<512, 256, 0, stream>>>(qb, kb, vtb, out);
}

// Round 4
// 199.834 us; speedup vs baseline: 1.0392x; 1.0254x over previous
//
#include <hip/hip_runtime.h>

typedef __attribute__((ext_vector_type(8))) short short8;
typedef __attribute__((ext_vector_type(4))) short short4v;
typedef __attribute__((ext_vector_type(4))) float floatx4;
typedef __attribute__((ext_vector_type(16))) float floatx16;
typedef __attribute__((ext_vector_type(2))) int iv2;

#define GLOBAL_AS __attribute__((address_space(1)))
#define LDS_AS __attribute__((address_space(3)))

__device__ __forceinline__ short f2bs(float f) {
    // RNE float -> bf16 (as short). Inputs finite here.
    union { float f; unsigned u; } v; v.f = f;
    unsigned r = v.u + 0x7fffu + ((v.u >> 16) & 1u);
    return (short)(r >> 16);
}

#if __has_builtin(__builtin_amdgcn_cvt_pk_bf16_f32)
typedef __attribute__((ext_vector_type(2))) __bf16 bf16x2;
__device__ __forceinline__ unsigned pk2(float a, float b) {
    union { bf16x2 v; unsigned u; } u;
    u.v = __builtin_amdgcn_cvt_pk_bf16_f32(a, b);
    return u.u;
}
#else
__device__ __forceinline__ unsigned pk2(float a, float b) {
    // round-half-up, non-negative finite inputs
    union { float f; unsigned u; } x, y; x.f = a; y.f = b;
    return ((y.u + 0x8000u) & 0xffff0000u) | ((x.u + 0x8000u) >> 16);
}
#endif

// ---------------- fused cast fp32 -> bf16 (x + Wq + Wk + Wv) ----------------
__global__ __launch_bounds__(256) void cast_all(const float* __restrict__ x,
                                                const float* __restrict__ Wq,
                                                const float* __restrict__ Wk,
                                                const float* __restrict__ Wv,
                                                short* __restrict__ xb,
                                                short* __restrict__ wb) {
    int b = blockIdx.x;
    int t = threadIdx.x;
    const float* src;
    short* dst;
    int idx;
    if (b < 8192) {
        src = x; dst = xb; idx = b * 1024 + t * 4;
    } else {
        int r = b - 8192;
        int wz = r >> 10;
        src = (wz == 0) ? Wq : (wz == 1) ? Wk : Wv;
        dst = wb + wz * (1 << 20);
        idx = (r & 1023) * 1024 + t * 4;
    }
    float4 v = *(const float4*)(src + idx);
    short4v o;
    o.x = f2bs(v.x); o.y = f2bs(v.y); o.z = f2bs(v.z); o.w = f2bs(v.w);
    *(short4v*)(dst + idx) = o;
}

// ---------------- QKV GEMM v3: 128x128 tile + K/V-style LDS double-buffer, counted vmcnt ----------------
// Same 128² tile / 4-wave / swizzle / epilogue as the proven R0 kernel; ONLY the K-loop schedule
// changes: loads for K-step T+1 stay in flight across the whole compute of step T.
// Per step: barrier(WAR buf[cur^1]) -> STAGE(buf[cur^1],T+1) -> vmcnt(8) -> barrier -> compute.
// Ledger (8 loads/STAGE, FIFO): steady outstanding 16, vmcnt(8) retires exactly tile-T's loads;
// vmcnt(0) only at T=15. LDS 64 KB -> 2 blocks/CU.
__global__ __launch_bounds__(256) void qkv_gemm(const short* __restrict__ xb,
                                                const short* __restrict__ wb,
                                                short* __restrict__ qout,
                                                short* __restrict__ kout,
                                                short* __restrict__ vtout) {
    __shared__ short As[2][128 * 64];  // [m][k], 16B chunks XOR-swizzled: slot = chunk ^ (row&7)
    __shared__ short Bs[2][128 * 64];
    const int K = 1024;
    int tid = threadIdx.x;
    int lane = tid & 63;
    int wid = tid >> 6;
    int quad = lane >> 4;
    int l16 = lane & 15;
    int wm = (wid >> 1) * 64;
    int wn = (wid & 1) * 64;
    int bm = blockIdx.x * 128;
    int bn = blockIdx.y * 128;
    const short* W = wb + (size_t)blockIdx.z * K * 1024;

    floatx4 acc[4][4];
#pragma unroll
    for (int i = 0; i < 4; i++)
#pragma unroll
        for (int j = 0; j < 4; j++) acc[i][j] = (floatx4){0.f, 0.f, 0.f, 0.f};

    int srow = tid >> 3;
    int ssw = ((tid & 7) ^ (srow & 7)) * 8;

#define STAGE_AB(cb, kk) do { \
    _Pragma("unroll") for (int l = 0; l < 4; l++) { \
        const short* g = xb + (size_t)(bm + srow + l * 32) * K + (kk) + ssw; \
        __builtin_amdgcn_global_load_lds((const GLOBAL_AS void*)g, \
            (LDS_AS void*)(&As[cb][0] + tid * 8 + l * 2048), 16, 0, 0); \
    } \
    _Pragma("unroll") for (int l = 0; l < 4; l++) { \
        const short* g = W + (size_t)(bn + srow + l * 32) * K + (kk) + ssw; \
        __builtin_amdgcn_global_load_lds((const GLOBAL_AS void*)g, \
            (LDS_AS void*)(&Bs[cb][0] + tid * 8 + l * 2048), 16, 0, 0); \
    } \
} while (0)

    STAGE_AB(0, 0);

    for (int T = 0; T < 16; T++) {
        int cur = T & 1;
        // WAR guard: all waves done reading buf[cur^1] (step T-1)
        __builtin_amdgcn_sched_barrier(0);
        __builtin_amdgcn_s_barrier();
        __builtin_amdgcn_sched_barrier(0);
        if (T < 15) {
            STAGE_AB(cur ^ 1, (T + 1) * 64);
            asm volatile("s_waitcnt vmcnt(8)" ::: "memory");  // step-T loads (mine) done
        } else {
            asm volatile("s_waitcnt vmcnt(0)" ::: "memory");
        }
        __builtin_amdgcn_sched_barrier(0);
        __builtin_amdgcn_s_barrier();   // step-T LDS visible to all waves
        __builtin_amdgcn_sched_barrier(0);

        const short* Ac = &As[cur][0];
        const short* Bc = &Bs[cur][0];
#pragma unroll
        for (int s = 0; s < 2; s++) {
            int slot = ((s * 4 + quad) ^ (l16 & 7)) * 8;
            short8 af[4], bf[4];
#pragma unroll
            for (int i = 0; i < 4; i++)
                af[i] = *(const short8*)(Ac + (wm + i * 16 + l16) * 64 + slot);
#pragma unroll
            for (int j = 0; j < 4; j++)
                bf[j] = *(const short8*)(Bc + (wn + j * 16 + l16) * 64 + slot);
#pragma unroll
            for (int i = 0; i < 4; i++)
#pragma unroll
                for (int j = 0; j < 4; j++)
                    acc[i][j] = __builtin_amdgcn_mfma_f32_16x16x32_bf16(af[i], bf[j], acc[i][j], 0, 0, 0);
        }
    }
#undef STAGE_AB

    if (blockIdx.z == 2) {
#pragma unroll
        for (int i = 0; i < 4; i++) {
#pragma unroll
            for (int j = 0; j < 4; j++) {
                int m = bm + wm + i * 16 + quad * 4;
                int c = bn + wn + j * 16 + l16;
                int b = m >> 11, nn = m & 2047, h = c >> 6, dd = c & 63;
                short4v pk;
                pk.x = f2bs(acc[i][j][0]);
                pk.y = f2bs(acc[i][j][1]);
                pk.z = f2bs(acc[i][j][2]);
                pk.w = f2bs(acc[i][j][3]);
                *(short4v*)(vtout + ((size_t)(b * 16 + h) * 64 + dd) * 2048 + nn) = pk;
            }
        }
    } else {
        short* dst = (blockIdx.z == 0) ? qout : kout;
        float qs = (blockIdx.z == 0) ? 0.180336881f : 1.0f;  // 0.125*log2(e) folded into Q
#pragma unroll
        for (int i = 0; i < 4; i++) {
#pragma unroll
            for (int j = 0; j < 4; j++) {
#pragma unroll
                for (int r = 0; r < 4; r++) {
                    int m = bm + wm + i * 16 + quad * 4 + r;
                    int c = bn + wn + j * 16 + l16;
                    dst[((size_t)((m >> 11) * 16 + (c >> 6)) * 2048 + (m & 2047)) * 64 + (c & 63)] =
                        f2bs(acc[i][j][r] * qs);
                }
            }
        }
    }
}

// ---------------- Flash attention v2b: in-register P (permlane32_swap) + K/V dbuf ----------------
// q: pre-scaled bf16 [b,h,2048,64]; k: [b,h,2048,64]; vt: [b,h,64,2048]; out fp32 [b,2048,1024]
// S^T = K*Q^T: lane owns ONE q-column. P never touches LDS.
// Exchange derivation (C/D map row=(e&3)+8(e>>2)+4*half): for K-step s (sb=s&1), consumer half h
// needs keys 16sb+8h+{0..7}, ALL from quad g=2sb+h: j0..3 from half-0 owner, j4..7 from half-1 owner.
// permlane32_swap(a=W[2sb], b=W[2sb+1]) -> r.x = {a_low, b_low} = j01/j23 dword for both halves,
// r.y = {a_high, b_high} = j45/j67 dword for both halves.
__global__ __launch_bounds__(256, 2) void attn(const short* __restrict__ q,
                                               const short* __restrict__ k,
                                               const short* __restrict__ vt,
                                               float* __restrict__ out) {
    __shared__ short Ks[2][128 * 64];   // [key][d], 16B slot = chunk ^ (key&7)
    __shared__ short Vs[2][64 * 128];   // [d][key], 16B slot = (c&8)|((c^(d&7))&7)

    int tid = threadIdx.x;
    int lane = tid & 63;
    int wid = tid >> 6;
    int l32 = lane & 31;
    int half = lane >> 5;   // 0/1

    int flat = blockIdx.x;
    int xcd = flat & 7;
    int slot = flat >> 3;            // 0..63
    int bh = xcd * 8 + (slot >> 3);  // 8 (b,h) per XCD
    int qx = slot & 7;
    int b = bh >> 4, h = bh & 15;

    const short* qp = q + (size_t)(b * 16 + h) * 2048 * 64;
    const short* kp = k + (size_t)(b * 16 + h) * 2048 * 64;
    const short* vp = vt + (size_t)(b * 16 + h) * 64 * 2048;

    // K staging: 128x64. row = (tid>>3)+l*32, chunk = tid&7 (swizzled at source)
    int krow = tid >> 3;
    int ksw = ((tid & 7) ^ (krow & 7)) * 8;
    // V staging: 64x128. d = (tid>>4)+l*16, chunk16 = tid&15
    int vd = tid >> 4;
    int vc = tid & 15;
    int vsw = ((vc & 8) | ((vc ^ vd) & 7)) * 8;

#define STAGE_KV(cb, kvb) do { \
    _Pragma("unroll") for (int l = 0; l < 4; l++) { \
        const short* g = kp + (size_t)((kvb) + krow + l * 32) * 64 + ksw; \
        __builtin_amdgcn_global_load_lds((const GLOBAL_AS void*)g, \
            (LDS_AS void*)(&Ks[cb][0] + tid * 8 + l * 2048), 16, 0, 0); \
    } \
    _Pragma("unroll") for (int l = 0; l < 4; l++) { \
        const short* g = vp + (size_t)(vd + l * 16) * 2048 + (kvb) + vsw; \
        __builtin_amdgcn_global_load_lds((const GLOBAL_AS void*)g, \
            (LDS_AS void*)(&Vs[cb][0] + tid * 8 + l * 2048), 16, 0, 0); \
    } \
} while (0)

    for (int phase = 0; phase < 2; phase++) {
        int qt = (phase == 0) ? qx : (15 - qx);
        int qbase = qt * 128;
        int qrow_w = qbase + wid * 32;      // wave owns q-rows qrow_w .. qrow_w+31
        int qlane = qrow_w + l32;           // this lane's q-row (S^T col)

        // Q fragments as B-operand: n = l32 (q-row), k = half*8 + j, 4 K-steps over d=64
        short8 qf[4];
#pragma unroll
        for (int s = 0; s < 4; s++)
            qf[s] = *(const short8*)(qp + (size_t)qlane * 64 + s * 16 + half * 8);

        floatx16 oacc[2];
#pragma unroll
        for (int nt = 0; nt < 2; nt++)
#pragma unroll
            for (int e = 0; e < 16; e++) oacc[nt][e] = 0.f;
        float rs = 0.f;

        int ntiles = qt + 1;

        // phase prologue: guard vs previous phase's reads of buf0, then stage tile 0
        __builtin_amdgcn_sched_barrier(0);
        __builtin_amdgcn_s_barrier();
        __builtin_amdgcn_sched_barrier(0);
        STAGE_KV(0, 0);

        for (int t = 0; t < ntiles; t++) {
            int cur = t & 1;
            int kvb = t * 128;

            // write-after-read guard: all waves done reading buf[cur^1] (tile t-1)
            __builtin_amdgcn_sched_barrier(0);
            __builtin_amdgcn_s_barrier();
            __builtin_amdgcn_sched_barrier(0);
            if (t + 1 < ntiles) {
                STAGE_KV(cur ^ 1, kvb + 128);
                asm volatile("s_waitcnt vmcnt(8)" ::: "memory");  // tile-t loads (mine) done
            } else {
                asm volatile("s_waitcnt vmcnt(0)" ::: "memory");
            }
            __builtin_amdgcn_sched_barrier(0);
            __builtin_amdgcn_s_barrier();   // tile-t LDS visible to all waves
            __builtin_amdgcn_sched_barrier(0);

            const short* Kc = &Ks[cur][0];
            const short* Vc = &Vs[cur][0];

            // ---- S^T[key 0..127][q 0..31] = K * Q^T ----
            floatx16 sacc[4];
#pragma unroll
            for (int kb = 0; kb < 4; kb++)
#pragma unroll
                for (int e = 0; e < 16; e++) sacc[kb][e] = 0.f;
#pragma unroll
            for (int s = 0; s < 4; s++) {   // d-dim K-steps
#pragma unroll
                for (int kb = 0; kb < 4; kb++) {
                    int key = kb * 32 + l32;
                    int c = s * 2 + half;
                    short8 kf = *(const short8*)(Kc + key * 64 + ((c ^ (key & 7)) * 8));
                    sacc[kb] = __builtin_amdgcn_mfma_f32_32x32x16_bf16(kf, qf[s], sacc[kb], 0, 0, 0);
                }
            }

            // ---- exp2 + mask (diag tile only) + local row-sum + in-register pack ----
            // quad g of block kb holds keys kb*32 + 8g + 4*half + {0..3} for q=l32:
            //   W0 = pk2(keys+0,+1), W1 = pk2(keys+2,+3)
            bool diag = (t == ntiles - 1) && (kvb + 127 > qrow_w);
            unsigned W0[4][4], W1[4][4];
#pragma unroll
            for (int kb = 0; kb < 4; kb++) {
#pragma unroll
                for (int e = 0; e < 16; e++) {
                    float p = __builtin_amdgcn_exp2f(sacc[kb][e]);
                    if (diag) {
                        int key = kvb + kb * 32 + (e & 3) + 8 * (e >> 2) + 4 * half;
                        p = (key > qlane) ? 0.f : p;
                    }
                    sacc[kb][e] = p;
                    rs += p;
                }
#pragma unroll
                for (int g = 0; g < 4; g++) {
                    W0[kb][g] = pk2(sacc[kb][4 * g + 0], sacc[kb][4 * g + 1]);
                    W1[kb][g] = pk2(sacc[kb][4 * g + 2], sacc[kb][4 * g + 3]);
                }
            }

            // ---- O += P * V : A-frag P[q=l32][keys 16s + 8*half + 0..7] via permlane32_swap ----
            // r0 = swap(W0[2sb], W0[2sb+1]): r0.x -> dword0 (keys +0,+1), r0.y -> dword2 (+4,+5)
            // r1 = swap(W1[2sb], W1[2sb+1]): r1.x -> dword1 (+2,+3),      r1.y -> dword3 (+6,+7)
#pragma unroll
            for (int s = 0; s < 8; s++) {   // key K-steps of 16
                int kb = s >> 1;
                int g0 = (s & 1) * 2;       // quad for half-0 consumers
                int g1 = g0 + 1;            // quad for half-1 consumers
                iv2 r0 = __builtin_amdgcn_permlane32_swap(W0[kb][g0], W0[kb][g1], false, false);
                iv2 r1 = __builtin_amdgcn_permlane32_swap(W1[kb][g0], W1[kb][g1], false, false);
                union { int4 v; short8 s8; } pu;
                pu.v.x = r0.x; pu.v.y = r1.x; pu.v.z = r0.y; pu.v.w = r1.y;
                short8 pf = pu.s8;
#pragma unroll
                for (int nt = 0; nt < 2; nt++) {
                    int d = nt * 32 + l32;
                    int c = s * 2 + half;
                    int sl = (c & 8) | ((c ^ (d & 7)) & 7);
                    short8 vf = *(const short8*)(Vc + d * 128 + sl * 8);
                    oacc[nt] = __builtin_amdgcn_mfma_f32_32x32x16_bf16(pf, vf, oacc[nt], 0, 0, 0);
                }
            }
        }

        // ---- epilogue: rows of O live across lanes; fetch 1/l via shuffle ----
        float tot = rs + __shfl_xor(rs, 32);
        float inv = 1.0f / tot;
        float invr[16];
#pragma unroll
        for (int e = 0; e < 16; e++)
            invr[e] = __shfl(inv, (e & 3) + 8 * (e >> 2) + 4 * half);
#pragma unroll
        for (int nt = 0; nt < 2; nt++) {
#pragma unroll
            for (int e = 0; e < 16; e++) {
                int r = (e & 3) + 8 * (e >> 2) + 4 * half;
                int nn = qrow_w + r;
                out[((size_t)b * 2048 + nn) * 1024 + h * 64 + nt * 32 + l32] = oacc[nt][e] * invr[e];
            }
        }
    }
#undef STAGE_KV
}

extern "C" void kernel_launch(void* const* d_in, const int* in_sizes, int n_in,
                              void* d_out, int out_size, void* d_ws, size_t ws_size,
                              hipStream_t stream) {
    const float* x = (const float*)d_in[0];
    const float* Wq = (const float*)d_in[1];
    const float* Wk = (const float*)d_in[2];
    const float* Wv = (const float*)d_in[3];
    float* out = (float*)d_out;
    char* ws = (char*)d_ws;

    short* xb = (short*)ws;                          // 16 MB: [8192,1024] bf16
    short* wb = (short*)(ws + (16u << 20));          //  6 MB: [3,1024,1024] bf16
    short* qb = (short*)(ws + (22u << 20));          // 16 MB: [4,16,2048,64]
    short* kb = (short*)(ws + (38u << 20));          // 16 MB: [4,16,2048,64]
    short* vtb = (short*)(ws + (54u << 20));         // 16 MB: [4,16,64,2048]

    cast_all<<<8192 + 3 * 1024, 256, 0, stream>>>(x, Wq, Wk, Wv, xb, wb);
    qkv_gemm<<<dim3(64, 8, 3), 256, 0, stream>>>(xb, wb, qb, kb, vtb);
    attn<<<512, 256, 0, stream>>>(qb, kb, vtb, out);
}